// Round 1
// baseline (41.469 us; speedup 1.0000x reference)
//
#include <hip/hip_runtime.h>

// Problem constants (match reference).
#define BB   64
#define NN   900
#define MM   300
#define NC1  92          // NUM_CLASSES + 1
#define MQ   (MM / 4)    // 75 float4 groups per row

__global__ __launch_bounds__(256) void cost_kernel(
    const float4* __restrict__ bbox_pred,   // [B*N] float4 (cx,cy,w,h)
    const float*  __restrict__ labels_pred, // [B*N*92]
    const float4* __restrict__ bbox_gt,     // [B*M] float4
    const int4*   __restrict__ labels_gt,   // [B*M/4]
    float4*       __restrict__ out)         // [B*N*M/4]
{
    const int total = BB * NN * MQ;
    int idx = blockIdx.x * blockDim.x + threadIdx.x;
    if (idx >= total) return;

    int mq = idx % MQ;
    int bn = idx / MQ;       // b*N + n
    int b  = bn / NN;

    // Per-(b,n) pred box: same for the whole group of 4 m's.
    float4 p = bbox_pred[bn];
    float pux = p.x - 0.5f * p.z, puy = p.y - 0.5f * p.w;
    float pdx = p.x + 0.5f * p.z, pdy = p.y + 0.5f * p.w;
    float pw = fmaxf(pdx - pux + 1.0f, 0.0f);
    float ph = fmaxf(pdy - puy + 1.0f, 0.0f);
    float p_area = pw * ph;

    int4 lg = labels_gt[b * MQ + mq];
    int lgj[4] = { lg.x, lg.y, lg.z, lg.w };
    const float* lp_row = labels_pred + (size_t)bn * NC1;

    float res[4];
#pragma unroll
    for (int j = 0; j < 4; ++j) {
        float4 g = bbox_gt[b * MM + mq * 4 + j];
        float gux = g.x - 0.5f * g.z, guy = g.y - 0.5f * g.w;
        float gdx = g.x + 0.5f * g.z, gdy = g.y + 0.5f * g.w;

        // L1 bbox loss on raw (cx,cy,w,h)
        float bbox_loss = fabsf(p.x - g.x) + fabsf(p.y - g.y)
                        + fabsf(p.z - g.z) + fabsf(p.w - g.w);

        // intersection
        float iwx = fmaxf(fminf(pdx, gdx) - fmaxf(pux, gux) + 1.0f, 0.0f);
        float iwy = fmaxf(fminf(pdy, gdy) - fmaxf(puy, guy) + 1.0f, 0.0f);
        float inter = iwx * iwy;

        // gt area
        float gw = fmaxf(gdx - gux + 1.0f, 0.0f);
        float gh = fmaxf(gdy - guy + 1.0f, 0.0f);
        float g_area = gw * gh;

        float uni = p_area + g_area - inter;
        float iou = inter / uni;

        // enclosing box
        float bwx = fmaxf(fmaxf(pdx, gdx) - fminf(pux, gux) + 1.0f, 0.0f);
        float bwy = fmaxf(fmaxf(pdy, gdy) - fminf(puy, guy) + 1.0f, 0.0f);
        float barea = bwx * bwy;
        float bg = (barea - uni) / barea;

        // iou_loss = -(iou - bg); class_loss = -lp
        float cls = lp_row[lgj[j]];
        res[j] = bbox_loss + (bg - iou) - cls;
    }

    out[idx] = make_float4(res[0], res[1], res[2], res[3]);
}

extern "C" void kernel_launch(void* const* d_in, const int* in_sizes, int n_in,
                              void* d_out, int out_size, void* d_ws, size_t ws_size,
                              hipStream_t stream) {
    const float4* bbox_pred   = (const float4*)d_in[0];
    const float*  labels_pred = (const float*) d_in[1];
    const float4* bbox_gt     = (const float4*)d_in[2];
    const int4*   labels_gt   = (const int4*)  d_in[3];
    float4*       out         = (float4*)d_out;

    const int total = BB * NN * MQ;           // 4,320,000 threads
    const int block = 256;
    const int grid  = (total + block - 1) / block;
    cost_kernel<<<grid, block, 0, stream>>>(bbox_pred, labels_pred, bbox_gt,
                                            labels_gt, out);
}

// Round 2
// 29.930 us; speedup vs baseline: 1.3856x; 1.3856x over previous
//
#include <hip/hip_runtime.h>

// Problem constants (match reference).
#define BB   64
#define NN   900
#define MM   300
#define NC1  92          // NUM_CLASSES + 1
#define MQ   (MM / 4)    // 75 float4 groups per row
#define KN   4           // n-values per thread (gt data reused across these)
#define NCH  (NN / KN)   // 225 n-chunks

__global__ __launch_bounds__(256) void cost_kernel(
    const float4* __restrict__ bbox_pred,   // [B*N] (cx,cy,w,h)
    const float*  __restrict__ labels_pred, // [B*N*92]
    const float4* __restrict__ bbox_gt,     // [B*M]
    const int4*   __restrict__ labels_gt,   // [B*M/4]
    float4*       __restrict__ out)         // [B*N*M/4]
{
    const int total = BB * NCH * MQ;
    int idx = blockIdx.x * blockDim.x + threadIdx.x;
    if (idx >= total) return;

    int mq   = idx % MQ;
    int rest = idx / MQ;
    int b    = rest / NCH;
    int nb   = rest % NCH;

    // ---- Load + derive gt state once; reuse for KN n-values ----
    int4 lg = labels_gt[b * MQ + mq];
    int lbl[4] = { lg.x, lg.y, lg.z, lg.w };

    float gx[4], gy[4], gz[4], gw_[4];
    float gux[4], guy[4], gdx[4], gdy[4], ga[4];
#pragma unroll
    for (int j = 0; j < 4; ++j) {
        float4 g = bbox_gt[b * MM + mq * 4 + j];
        gx[j] = g.x; gy[j] = g.y; gz[j] = g.z; gw_[j] = g.w;
        gux[j] = g.x - 0.5f * g.z;  guy[j] = g.y - 0.5f * g.w;
        gdx[j] = g.x + 0.5f * g.z;  gdy[j] = g.y + 0.5f * g.w;
        float gwd = fmaxf(gdx[j] - gux[j] + 1.0f, 0.0f);
        float ghd = fmaxf(gdy[j] - guy[j] + 1.0f, 0.0f);
        ga[j] = gwd * ghd;
    }

#pragma unroll
    for (int k = 0; k < KN; ++k) {
        int n  = nb * KN + k;
        int bn = b * NN + n;

        float4 p = bbox_pred[bn];
        float pux = p.x - 0.5f * p.z, puy = p.y - 0.5f * p.w;
        float pdx = p.x + 0.5f * p.z, pdy = p.y + 0.5f * p.w;
        float pw = fmaxf(pdx - pux + 1.0f, 0.0f);
        float ph = fmaxf(pdy - puy + 1.0f, 0.0f);
        float p_area = pw * ph;

        const float* lp_row = labels_pred + (size_t)bn * NC1;

        float res[4];
#pragma unroll
        for (int j = 0; j < 4; ++j) {
            // L1 bbox loss on raw (cx,cy,w,h)
            float bbox_loss = fabsf(p.x - gx[j]) + fabsf(p.y - gy[j])
                            + fabsf(p.z - gz[j]) + fabsf(p.w - gw_[j]);

            // intersection
            float iwx = fmaxf(fminf(pdx, gdx[j]) - fmaxf(pux, gux[j]) + 1.0f, 0.0f);
            float iwy = fmaxf(fminf(pdy, gdy[j]) - fmaxf(puy, guy[j]) + 1.0f, 0.0f);
            float inter = iwx * iwy;

            float uni = p_area + ga[j] - inter;
            float iou = inter * __builtin_amdgcn_rcpf(uni);

            // enclosing box
            float bwx = fmaxf(fmaxf(pdx, gdx[j]) - fminf(pux, gux[j]) + 1.0f, 0.0f);
            float bwy = fmaxf(fmaxf(pdy, gdy[j]) - fminf(puy, guy[j]) + 1.0f, 0.0f);
            float barea = bwx * bwy;
            float bg = (barea - uni) * __builtin_amdgcn_rcpf(barea);

            float cls = lp_row[lbl[j]];
            res[j] = bbox_loss + (bg - iou) - cls;
        }

        out[(size_t)bn * MQ + mq] = make_float4(res[0], res[1], res[2], res[3]);
    }
}

extern "C" void kernel_launch(void* const* d_in, const int* in_sizes, int n_in,
                              void* d_out, int out_size, void* d_ws, size_t ws_size,
                              hipStream_t stream) {
    const float4* bbox_pred   = (const float4*)d_in[0];
    const float*  labels_pred = (const float*) d_in[1];
    const float4* bbox_gt     = (const float4*)d_in[2];
    const int4*   labels_gt   = (const int4*)  d_in[3];
    float4*       out         = (float4*)d_out;

    const int total = BB * NCH * MQ;          // 1,080,000 threads, 16 outputs each
    const int block = 256;
    const int grid  = (total + block - 1) / block;
    cost_kernel<<<grid, block, 0, stream>>>(bbox_pred, labels_pred, bbox_gt,
                                            labels_gt, out);
}

// Round 4
// 28.367 us; speedup vs baseline: 1.4619x; 1.0551x over previous
//
#include <hip/hip_runtime.h>

// Problem constants (match reference).
#define BB   64
#define NN   900
#define MM   300
#define NC1  92          // NUM_CLASSES + 1
#define MQ   (MM / 4)    // 75 float4 groups per row
#define KN   6           // n-values per thread (gt state reused across these)
#define NCH  (NN / KN)   // 150 n-chunks

typedef float floatx4 __attribute__((ext_vector_type(4)));  // native vec for NT store

__global__ __launch_bounds__(256) void cost_kernel(
    const float4* __restrict__ bbox_pred,   // [B*N] (cx,cy,w,h)
    const float*  __restrict__ labels_pred, // [B*N*92]
    const float4* __restrict__ bbox_gt,     // [B*M]
    const int4*   __restrict__ labels_gt,   // [B*M/4]
    floatx4*      __restrict__ out)         // [B*N*M/4]
{
    const int total = BB * NCH * MQ;
    int idx = blockIdx.x * blockDim.x + threadIdx.x;
    if (idx >= total) return;

    int mq   = idx % MQ;
    int rest = idx / MQ;
    int b    = rest / NCH;
    int nb   = rest % NCH;

    // ---- gt state: load + derive once, reuse for KN n-rows ----
    int4 lg = labels_gt[b * MQ + mq];
    int lbl[4] = { lg.x, lg.y, lg.z, lg.w };

    float gx[4], gy[4], gz[4], gw_[4];          // raw for L1 loss
    float gux[4], guy[4], gdx1[4], gdy1[4];     // corners (+1 folded into dr)
    float gz1[4], gw1[4], ga[4];                // w+1, h+1, area
#pragma unroll
    for (int j = 0; j < 4; ++j) {
        float4 g = bbox_gt[b * MM + mq * 4 + j];
        gx[j] = g.x; gy[j] = g.y; gz[j] = g.z; gw_[j] = g.w;
        gux[j]  = g.x - 0.5f * g.z;   guy[j]  = g.y - 0.5f * g.w;
        gdx1[j] = g.x + 0.5f * g.z + 1.0f;
        gdy1[j] = g.y + 0.5f * g.w + 1.0f;
        gz1[j]  = g.z + 1.0f;         gw1[j]  = g.w + 1.0f;
        ga[j]   = gz1[j] * gw1[j];    // g_wh clamps are no-ops: w,h >= 0
    }

#pragma unroll
    for (int k = 0; k < KN; ++k) {
        int bn = b * NN + nb * KN + k;

        float4 p = bbox_pred[bn];
        float pux  = p.x - 0.5f * p.z,  puy  = p.y - 0.5f * p.w;
        float pdx1 = p.x + 0.5f * p.z + 1.0f;
        float pdy1 = p.y + 0.5f * p.w + 1.0f;
        float pz1  = p.z + 1.0f,        pw1  = p.w + 1.0f;
        float p_area = pz1 * pw1;

        const float* lp_row = labels_pred + (size_t)bn * NC1;

        float res[4];
#pragma unroll
        for (int j = 0; j < 4; ++j) {
            // intersection (raw, +1 already folded into *dx1)
            float iwrx = fminf(pdx1, gdx1[j]) - fmaxf(pux, gux[j]);
            float iwry = fminf(pdy1, gdy1[j]) - fmaxf(puy, guy[j]);
            float iwx  = fmaxf(iwrx, 0.0f);
            float iwy  = fmaxf(iwry, 0.0f);
            float inter = iwx * iwy;

            // bound via sum identity: iw_raw + bw = (pz+1)+(gz+1)
            float bwx = (pz1 + gz1[j]) - iwrx;
            float bwy = (pw1 + gw1[j]) - iwry;
            float barea = bwx * bwy;

            float uni = (p_area + ga[j]) - inter;
            float iou = inter * __builtin_amdgcn_rcpf(uni);
            float t   = uni   * __builtin_amdgcn_rcpf(barea);  // bg = 1 - t

            float bbox = fabsf(p.x - gx[j]) + fabsf(p.y - gy[j])
                       + fabsf(p.z - gz[j]) + fabsf(p.w - gw_[j]);

            float cls = lp_row[lbl[j]];
            res[j] = bbox + (1.0f - cls) - t - iou;
        }

        floatx4 v = { res[0], res[1], res[2], res[3] };
        __builtin_nontemporal_store(v, &out[(size_t)bn * MQ + mq]);
    }
}

extern "C" void kernel_launch(void* const* d_in, const int* in_sizes, int n_in,
                              void* d_out, int out_size, void* d_ws, size_t ws_size,
                              hipStream_t stream) {
    const float4* bbox_pred   = (const float4*)d_in[0];
    const float*  labels_pred = (const float*) d_in[1];
    const float4* bbox_gt     = (const float4*)d_in[2];
    const int4*   labels_gt   = (const int4*)  d_in[3];
    floatx4*      out         = (floatx4*)d_out;

    const int total = BB * NCH * MQ;          // 720,000 threads, 24 outputs each
    const int block = 256;
    const int grid  = (total + block - 1) / block;
    cost_kernel<<<grid, block, 0, stream>>>(bbox_pred, labels_pred, bbox_gt,
                                            labels_gt, out);
}

// Round 5
// 27.349 us; speedup vs baseline: 1.5163x; 1.0372x over previous
//
#include <hip/hip_runtime.h>

// Problem constants (match reference).
#define BB   64
#define NN   900
#define MM   300
#define NC1  92          // NUM_CLASSES + 1
#define MQ   (MM / 4)    // 75 float4 groups per row
#define KN   4           // n-rows per thread
#define NCH  (NN / KN)   // 225 n-chunks

__global__ __launch_bounds__(256) void cost_kernel(
    const float4* __restrict__ bbox_pred,   // [B*N] (cx,cy,w,h)
    const float*  __restrict__ labels_pred, // [B*N*92]
    const float4* __restrict__ bbox_gt,     // [B*M]
    const int4*   __restrict__ labels_gt,   // [B*M/4]
    float4*       __restrict__ out)         // [B*N*M/4]
{
    const int total = BB * NCH * MQ;
    int idx = blockIdx.x * blockDim.x + threadIdx.x;
    if (idx >= total) return;

    int mq   = idx % MQ;
    int rest = idx / MQ;
    int b    = rest / NCH;
    int nb   = rest % NCH;
    int bn0  = b * NN + nb * KN;

    // ---------- Phase 1: issue ALL loads up front (2 dependent round trips) ----------
    int4 lg = labels_gt[b * MQ + mq];                 // round trip 1 (feeds gathers)

    float4 g4[4];
#pragma unroll
    for (int j = 0; j < 4; ++j)
        g4[j] = bbox_gt[b * MM + mq * 4 + j];

    float4 p4[KN];
#pragma unroll
    for (int k = 0; k < KN; ++k)
        p4[k] = bbox_pred[bn0 + k];

    int lbl[4] = { lg.x, lg.y, lg.z, lg.w };

    float cls[KN][4];                                 // round trip 2: all gathers in flight
#pragma unroll
    for (int k = 0; k < KN; ++k) {
        const float* lp = labels_pred + (size_t)(bn0 + k) * NC1;
#pragma unroll
        for (int j = 0; j < 4; ++j)
            cls[k][j] = lp[lbl[j]];
    }

    // ---------- Phase 2: gt-derived state (overlaps gather latency) ----------
    float gx[4], gy[4], gz[4], gw_[4];
    float gux[4], guy[4], gdx1[4], gdy1[4];
    float gz1[4], gw1[4], ga[4];
#pragma unroll
    for (int j = 0; j < 4; ++j) {
        float4 g = g4[j];
        gx[j] = g.x; gy[j] = g.y; gz[j] = g.z; gw_[j] = g.w;
        gux[j]  = g.x - 0.5f * g.z;   guy[j]  = g.y - 0.5f * g.w;
        gdx1[j] = g.x + 0.5f * g.z + 1.0f;
        gdy1[j] = g.y + 0.5f * g.w + 1.0f;
        gz1[j]  = g.z + 1.0f;         gw1[j]  = g.w + 1.0f;
        ga[j]   = gz1[j] * gw1[j];    // clamps are no-ops: w,h >= 0
    }

    // ---------- Phase 3: pure-VALU compute + stores ----------
#pragma unroll
    for (int k = 0; k < KN; ++k) {
        float4 p = p4[k];
        float pux  = p.x - 0.5f * p.z,  puy  = p.y - 0.5f * p.w;
        float pdx1 = p.x + 0.5f * p.z + 1.0f;
        float pdy1 = p.y + 0.5f * p.w + 1.0f;
        float pz1  = p.z + 1.0f,        pw1  = p.w + 1.0f;
        float p_area = pz1 * pw1;

        float res[4];
#pragma unroll
        for (int j = 0; j < 4; ++j) {
            float iwrx = fminf(pdx1, gdx1[j]) - fmaxf(pux, gux[j]);
            float iwry = fminf(pdy1, gdy1[j]) - fmaxf(puy, guy[j]);
            float iwx  = fmaxf(iwrx, 0.0f);
            float iwy  = fmaxf(iwry, 0.0f);
            float inter = iwx * iwy;

            // bound via sum identity: iw_raw + bw = (pz+1)+(gz+1)
            float bwx = (pz1 + gz1[j]) - iwrx;
            float bwy = (pw1 + gw1[j]) - iwry;
            float barea = bwx * bwy;

            float uni = (p_area + ga[j]) - inter;
            float iou = inter * __builtin_amdgcn_rcpf(uni);
            float t   = uni   * __builtin_amdgcn_rcpf(barea);  // bg = 1 - t

            float bbox = fabsf(p.x - gx[j]) + fabsf(p.y - gy[j])
                       + fabsf(p.z - gz[j]) + fabsf(p.w - gw_[j]);

            res[j] = bbox + (1.0f - cls[k][j]) - t - iou;
        }

        out[(size_t)(bn0 + k) * MQ + mq] = make_float4(res[0], res[1], res[2], res[3]);
    }
}

extern "C" void kernel_launch(void* const* d_in, const int* in_sizes, int n_in,
                              void* d_out, int out_size, void* d_ws, size_t ws_size,
                              hipStream_t stream) {
    const float4* bbox_pred   = (const float4*)d_in[0];
    const float*  labels_pred = (const float*) d_in[1];
    const float4* bbox_gt     = (const float4*)d_in[2];
    const int4*   labels_gt   = (const int4*)  d_in[3];
    float4*       out         = (float4*)d_out;

    const int total = BB * NCH * MQ;          // 1,080,000 threads, 16 outputs each
    const int block = 256;
    const int grid  = (total + block - 1) / block;
    cost_kernel<<<grid, block, 0, stream>>>(bbox_pred, labels_pred, bbox_gt,
                                            labels_gt, out);
}